// Round 20
// baseline (168.539 us; speedup 1.0000x reference)
//
#include <hip/hip_runtime.h>
#include <hip/hip_bf16.h>
#include <hip/hip_fp8.h>
#include <math.h>

#define N 4096
#define D 1024
#define NINST 8
#define NGROUP (N / NINST)
#define ALPHA 20.0f
#define MARGIN 0.5f
#define NB 64            // 64-row bands
#define NTILE (NB * (NB + 1) / 2)   // 2080 triangular tiles

typedef __attribute__((ext_vector_type(4))) float f32x4;

__device__ __forceinline__ unsigned fkey(float f) {
    int b = __float_as_int(f);
    return (b >= 0) ? ((unsigned)b | 0x80000000u) : ~(unsigned)b;
}
__device__ __forceinline__ float fdec(unsigned u) {
    int b = (u & 0x80000000u) ? (int)(u ^ 0x80000000u) : ~(int)u;
    return __int_as_float(b);
}

// stable fast softplus: log1p(exp(x)) = max(x,0) + log(1 + exp(-|x|))
__device__ __forceinline__ float softplus(float x) {
    float z = __expf(-fabsf(x));
    return fmaxf(x, 0.0f) + __logf(1.0f + z);
}

// async global -> LDS, 16 bytes per lane (lds dest: wave-uniform base + lane*16)
__device__ __forceinline__ void gld16(const void* g, void* l) {
    __builtin_amdgcn_global_load_lds(
        (const __attribute__((address_space(1))) void*)g,
        (__attribute__((address_space(3))) void*)l, 16, 0, 0);
}

// ---------------- K1: per-group normalize + banded fragment-major fp8 write + fp32 Gram ----
// (R17 512-thread version, unchanged.) xn8 layout (ulong units): idx = band64*8192 +
// kstep*256 + m*64 + slot; band64 = row>>6, m = (row>>4)&3, slot = oct*16 + (row&15).
__global__ __launch_bounds__(512) void k_normpos(const float* __restrict__ in,
                                                 unsigned long* __restrict__ xn8,
                                                 float* __restrict__ pos_sims,
                                                 float* __restrict__ min_pos,
                                                 unsigned* __restrict__ gmax,
                                                 float* __restrict__ accum,
                                                 unsigned* __restrict__ cnt) {
    __shared__ float4 srows4[8 * 257];
    __shared__ float spart[8][4];
    __shared__ float sinv[8];
    __shared__ float sg[8][8];

    int g = blockIdx.x;
    int t = threadIdx.x;
    int lane = t & 63;
    int w = t >> 6;
    int par = t >> 8;

    if (g == 0) {
        if (t == 0) { *gmax = 0u; *cnt = 0u; }
        if (t < 32) accum[t] = 0.f;
    }

    const float4* in4 = (const float4*)in;
    #pragma unroll
    for (int k = 0; k < 4; ++k) {
        float4 v = in4[(size_t)g * 2048 + k * 512 + t];
        int row = 2 * k + par;
        srows4[row * 257 + (t & 255)] = v;
        float ss = v.x * v.x + v.y * v.y + v.z * v.z + v.w * v.w;
        #pragma unroll
        for (int off = 1; off < 64; off <<= 1) ss += __shfl_xor(ss, off);
        if (lane == 0) spart[row][w & 3] = ss;
    }
    __syncthreads();
    if (t < 8) sinv[t] = rsqrtf(spart[t][0] + spart[t][1] + spart[t][2] + spart[t][3]);
    __syncthreads();

    {
        int i_row = t & 7;
        int oct  = (t >> 3) & 3;
        int k0b  = (t >> 5) & 7;
        int hi   = t >> 8;
        size_t base = (size_t)(g >> 3) * 8192 + (size_t)((g >> 1) & 3) * 64
                    + (size_t)(oct * 16 + (g & 1) * 8 + i_row);
        float inv = sinv[i_row];
        #pragma unroll
        for (int jj = 0; jj < 2; ++jj) {
            int k0 = k0b + (hi * 2 + jj) * 8;
            float4 v0 = srows4[i_row * 257 + k0 * 8 + oct * 2];
            float4 v1 = srows4[i_row * 257 + k0 * 8 + oct * 2 + 1];
            union { unsigned char c[8]; unsigned long u64; } o;
            o.c[0] = __hip_fp8_e4m3(v0.x * inv).__x;
            o.c[1] = __hip_fp8_e4m3(v0.y * inv).__x;
            o.c[2] = __hip_fp8_e4m3(v0.z * inv).__x;
            o.c[3] = __hip_fp8_e4m3(v0.w * inv).__x;
            o.c[4] = __hip_fp8_e4m3(v1.x * inv).__x;
            o.c[5] = __hip_fp8_e4m3(v1.y * inv).__x;
            o.c[6] = __hip_fp8_e4m3(v1.z * inv).__x;
            o.c[7] = __hip_fp8_e4m3(v1.w * inv).__x;
            xn8[base + (size_t)k0 * 256] = o.u64;
        }
    }

    int pair = t >> 3, a = pair >> 3, b = pair & 7, slice = t & 7;
    const float4* pa = srows4 + a * 257 + slice * 32;
    const float4* pb = srows4 + b * 257 + slice * 32;
    int j0 = ((pair << 1) + slice) & 31;
    float s = 0.f;
    #pragma unroll 8
    for (int i = 0; i < 32; ++i) {
        int j = (i + j0) & 31;
        float4 x = pa[j], y = pb[j];
        s += x.x * y.x + x.y * y.y + x.z * y.z + x.w * y.w;
    }
    s += __shfl_xor(s, 1);
    s += __shfl_xor(s, 2);
    s += __shfl_xor(s, 4);
    if (slice == 0) sg[a][b] = s * sinv[a] * sinv[b];
    __syncthreads();
    if (t < 8) {
        float mn = 1e30f;
        int idx = 0;
        #pragma unroll
        for (int b2 = 0; b2 < 8; ++b2) {
            if (b2 == t) continue;
            float v = sg[t][b2];
            mn = fminf(mn, v);
            pos_sims[(size_t)(g * 8 + t) * 8 + idx] = v;
            ++idx;
        }
        min_pos[g * 8 + t] = mn;
    }
}

// ---------------- K2: fp8 MFMA sim tiles, ONE-SHOT staged 64x64 tiles ----------
// grid 2080 x 256 thr (4 waves, 2x2). Whole A-band (64KB) + B-band (64KB) staged in
// ONE burst (32 gld16/wave, contiguous), ONE vmcnt(0)+barrier, then the full K=1024
// loop runs from LDS with no syncs. DMA latency paid once per block (was 32x).
// Wave (wr,wc) owns a 32x32 quadrant: 128 MFMA, acc[2][2]. Epilogue combines wave
// halves in LDS, preserving the 64-slot map (row slot=ct, col slot=rt).
__global__ __launch_bounds__(256) void k_neg(const unsigned long* __restrict__ xn8,
                                             const float* __restrict__ min_pos,
                                             float* __restrict__ sum_part,
                                             int* __restrict__ cnt_part,
                                             float* __restrict__ max_part,
                                             unsigned* __restrict__ gmax) {
    __shared__ __align__(16) char panels[131072];   // A [0,64K) | B [64K,128K)
    __shared__ float sMinA[64], sMinB[64];
    __shared__ float sRS[2][64]; __shared__ int sRC[2][64]; __shared__ float sRM[2][64];
    __shared__ float sCS[2][64]; __shared__ int sCC[2][64]; __shared__ float sCM[2][64];

    int bid = blockIdx.x;
    int rt = 0, rem = bid;
    while (rem >= NB - rt) { rem -= NB - rt; ++rt; }
    int ct = rt + rem;
    bool diag = (rt == ct);

    int R0 = rt * 64, C0 = ct * 64;
    int t = threadIdx.x, l = t & 63, w = t >> 6;
    int wr = w >> 1, wc = w & 1;
    int lrow = l & 15, kgrp = l >> 4;

    if (t < 64) sMinA[t] = min_pos[R0 + t];
    else if (t < 128) sMinB[t - 64] = min_pos[C0 + (t - 64)];

    // one-shot stage: wave w stages its 32 KB quarter (contiguous 1KB gld16 x32)
    {
        const char* xb = (const char*)xn8;
        const char* src = (w < 2)
            ? xb + (size_t)rt * 65536 + (size_t)w * 32768
            : xb + (size_t)ct * 65536 + (size_t)(w - 2) * 32768;
        char* dst = panels + (size_t)w * 32768;
        #pragma unroll
        for (int j = 0; j < 32; ++j)
            gld16(src + (size_t)j * 1024 + (size_t)l * 16, dst + (size_t)j * 1024);
    }
    asm volatile("s_waitcnt vmcnt(0)" ::: "memory");
    __syncthreads();   // all panels + sMin visible

    // compute: 32 ksteps, no syncs. Fragment (k,m): byte k*2048 + m*512 + l*8.
    f32x4 zero = {0.f, 0.f, 0.f, 0.f};
    f32x4 acc[2][2];
    #pragma unroll
    for (int m = 0; m < 2; ++m)
        #pragma unroll
        for (int n = 0; n < 2; ++n) acc[m][n] = zero;

    const char* pA = panels + (size_t)wr * 1024 + (size_t)l * 8;
    const char* pB = panels + 65536 + (size_t)wc * 1024 + (size_t)l * 8;

    #pragma unroll 4
    for (int k = 0; k < 32; ++k) {
        long a0 = *(const long*)(pA + (size_t)k * 2048);
        long a1 = *(const long*)(pA + (size_t)k * 2048 + 512);
        long b0 = *(const long*)(pB + (size_t)k * 2048);
        long b1 = *(const long*)(pB + (size_t)k * 2048 + 512);
        acc[0][0] = __builtin_amdgcn_mfma_f32_16x16x32_fp8_fp8(a0, b0, acc[0][0], 0, 0, 0);
        acc[0][1] = __builtin_amdgcn_mfma_f32_16x16x32_fp8_fp8(a0, b1, acc[0][1], 0, 0, 0);
        acc[1][0] = __builtin_amdgcn_mfma_f32_16x16x32_fp8_fp8(a1, b0, acc[1][0], 0, 0, 0);
        acc[1][1] = __builtin_amdgcn_mfma_f32_16x16x32_fp8_fp8(a1, b1, acc[1][1], 0, 0, 0);
    }

    // ---- epilogue: per-wave quadrant stats -> LDS combine -> 64-slot writes ----
    float allmax = -1e30f;

    float thB[2];
    #pragma unroll
    for (int n = 0; n < 2; ++n) thB[n] = sMinB[wc * 32 + n * 16 + lrow] - 0.05f;

    float colS[2] = {0.f, 0.f};
    float colM[2] = {-1e30f, -1e30f};
    int   colC[2] = {0, 0};

    #pragma unroll
    for (int m = 0; m < 2; ++m) {
        #pragma unroll
        for (int reg = 0; reg < 4; ++reg) {
            int lr32 = m * 16 + kgrp * 4 + reg;       // row within quadrant [0,32)
            int lr = wr * 32 + lr32;                  // row within band [0,64)
            int grow = R0 + lr;
            float th = sMinA[lr] - 0.05f;
            int gi = grow >> 3;
            float rs = 0.f, rm = -1e30f;
            int rc = 0;
            #pragma unroll
            for (int n = 0; n < 2; ++n) {
                int gcol = C0 + wc * 32 + n * 16 + lrow;
                float s = acc[m][n][reg];
                allmax = fmaxf(allmax, s);
                if ((gcol >> 3) != gi) {
                    float e = softplus(ALPHA * (s - MARGIN));
                    rm = fmaxf(rm, s);
                    if (s > th) { rs += e; rc += 1; }
                    if (!diag) {
                        colM[n] = fmaxf(colM[n], s);
                        if (s > thB[n]) { colS[n] += e; colC[n] += 1; }
                    }
                }
            }
            // reduce across the 16 col-lanes (same kgrp group)
            #pragma unroll
            for (int off = 1; off < 16; off <<= 1) {
                rs += __shfl_xor(rs, off);
                rc += __shfl_xor(rc, off);
                rm = fmaxf(rm, __shfl_xor(rm, off));
            }
            if (lrow == 0) { sRS[wc][lr] = rs; sRC[wc][lr] = rc; sRM[wc][lr] = rm; }
        }
    }

    if (!diag) {
        // col stats: reduce across the 4 kgrp lane-groups
        #pragma unroll
        for (int n = 0; n < 2; ++n) {
            float cs = colS[n], cm = colM[n];
            int cc = colC[n];
            cs += __shfl_xor(cs, 16); cs += __shfl_xor(cs, 32);
            cc += __shfl_xor(cc, 16); cc += __shfl_xor(cc, 32);
            cm = fmaxf(cm, __shfl_xor(cm, 16));
            cm = fmaxf(cm, __shfl_xor(cm, 32));
            if (kgrp == 0) {
                int lc = wc * 32 + n * 16 + lrow;     // col within band [0,64)
                sCS[wr][lc] = cs; sCC[wr][lc] = cc; sCM[wr][lc] = cm;
            }
        }
    }
    __syncthreads();

    if (t < 64) {
        int r = t;
        float rs = sRS[0][r] + sRS[1][r];
        int   rc = sRC[0][r] + sRC[1][r];
        float rm = fmaxf(sRM[0][r], sRM[1][r]);
        sum_part[(size_t)(R0 + r) * 64 + ct] = rs;
        cnt_part[(size_t)(R0 + r) * 64 + ct] = rc;
        max_part[(size_t)(R0 + r) * 64 + ct] = rm;
    } else if (t < 128 && !diag) {
        int c = t - 64;
        float cs = sCS[0][c] + sCS[1][c];
        int   cc = sCC[0][c] + sCC[1][c];
        float cm = fmaxf(sCM[0][c], sCM[1][c]);
        sum_part[(size_t)(C0 + c) * 64 + rt] = cs;
        cnt_part[(size_t)(C0 + c) * 64 + rt] = cc;
        max_part[(size_t)(C0 + c) * 64 + rt] = cm;
    }

    #pragma unroll
    for (int off = 1; off < 64; off <<= 1) allmax = fmaxf(allmax, __shfl_xor(allmax, off));
    if (l == 0) atomicMax(gmax, fkey(allmax));
}

// ---------------- K3: per-row combine (64 slots/row) + spread-atomic final mean ----------------
__global__ __launch_bounds__(256) void k_rowfinal(const float* __restrict__ sum_part,
                                                  const int* __restrict__ cnt_part,
                                                  const float* __restrict__ max_part,
                                                  const float* __restrict__ pos_sims,
                                                  const float* __restrict__ min_pos,
                                                  const unsigned* __restrict__ gmax,
                                                  float* __restrict__ accum,
                                                  unsigned* __restrict__ cnt,
                                                  float* __restrict__ out) {
    __shared__ float sloss[4];
    int row = blockIdx.x * 4 + (threadIdx.x >> 6);
    int lane = threadIdx.x & 63;
    float ns = sum_part[(size_t)row * 64 + lane];
    int nc = cnt_part[(size_t)row * 64 + lane];
    float nm = max_part[(size_t)row * 64 + lane];
    #pragma unroll
    for (int off = 1; off < 64; off <<= 1) {
        ns += __shfl_xor(ns, off);
        nc += __shfl_xor(nc, off);
        nm = fmaxf(nm, __shfl_xor(nm, off));
    }
    if (lane == 0) {
        float base = fmaxf(fdec(*gmax) - 0.1f, MARGIN + 0.2f);
        float neg_loss = (nc > 0) ? ns / (float)nc : softplus(ALPHA * (nm - MARGIN));
        float ps = 0.f;
        int pcnt = 0;
        float mn = min_pos[row];
        #pragma unroll
        for (int i = 0; i < NINST - 1; ++i) {
            float s = pos_sims[(size_t)row * 8 + i];
            if (s < base) { ps += softplus(-2.0f * (s - MARGIN)); pcnt++; }
        }
        float pos_loss = (pcnt > 0) ? ps / (float)pcnt : softplus(-2.0f * (mn - MARGIN));
        sloss[threadIdx.x >> 6] = pos_loss + neg_loss;
    }
    __syncthreads();
    if (threadIdx.x == 0) {
        float bs = sloss[0] + sloss[1] + sloss[2] + sloss[3];
        atomicAdd(&accum[blockIdx.x & 31], bs);
        __threadfence();
        unsigned old = atomicAdd(cnt, 1u);
        if (old == gridDim.x - 1) {
            __threadfence();
            float tot = 0.f;
            for (int j = 0; j < 32; ++j) tot += atomicAdd(&accum[j], 0.0f);
            out[0] = tot / (float)N;
        }
    }
}

extern "C" void kernel_launch(void* const* d_in, const int* in_sizes, int n_in,
                              void* d_out, int out_size, void* d_ws, size_t ws_size,
                              hipStream_t stream) {
    const float* in = (const float*)d_in[0];
    float* out = (float*)d_out;

    char* ws = (char*)d_ws;
    unsigned long* xn8 = (unsigned long*)(ws);                  // 4 MB (banded fragment-major)
    float*   min_pos  = (float*)(ws + 8388608 + 16384);         // 16 KB
    float*   pos_sims = (float*)(ws + 8388608 + 32768);         // 128 KB
    float*   sum_part = (float*)(ws + 8388608 + 32768 + 131072);            // 1 MB
    float*   max_part = (float*)(ws + 8388608 + 32768 + 131072 + 1048576);  // 1 MB
    int*     cnt_part = (int*)  (ws + 8388608 + 32768 + 131072 + 2097152);  // 1 MB
    unsigned* gmax    = (unsigned*)(ws + 8388608 + 32768 + 131072 + 3145728);
    float*   accum    = (float*)(ws + 8388608 + 32768 + 131072 + 3145728 + 128);  // 32 floats
    unsigned* cnt     = (unsigned*)(ws + 8388608 + 32768 + 131072 + 3145728 + 256);

    k_normpos<<<NGROUP, 512, 0, stream>>>(in, xn8, pos_sims, min_pos, gmax, accum, cnt);
    k_neg<<<NTILE, 256, 0, stream>>>(xn8, min_pos, sum_part, cnt_part, max_part, gmax);
    k_rowfinal<<<N / 4, 256, 0, stream>>>(sum_part, cnt_part, max_part, pos_sims, min_pos,
                                          gmax, accum, cnt, out);
}

// Round 21
// 119.348 us; speedup vs baseline: 1.4122x; 1.4122x over previous
//
#include <hip/hip_runtime.h>
#include <hip/hip_bf16.h>
#include <hip/hip_fp8.h>
#include <math.h>

#define N 4096
#define D 1024
#define NINST 8
#define NGROUP (N / NINST)
#define ALPHA 20.0f
#define MARGIN 0.5f
#define NB 64            // 64-row bands
#define NTILE (NB * (NB + 1) / 2)   // 2080 triangular tiles

typedef __attribute__((ext_vector_type(4))) float f32x4;

__device__ __forceinline__ unsigned fkey(float f) {
    int b = __float_as_int(f);
    return (b >= 0) ? ((unsigned)b | 0x80000000u) : ~(unsigned)b;
}
__device__ __forceinline__ float fdec(unsigned u) {
    int b = (u & 0x80000000u) ? (int)(u ^ 0x80000000u) : ~(int)u;
    return __int_as_float(b);
}

// stable fast softplus: log1p(exp(x)) = max(x,0) + log(1 + exp(-|x|))
__device__ __forceinline__ float softplus(float x) {
    float z = __expf(-fabsf(x));
    return fmaxf(x, 0.0f) + __logf(1.0f + z);
}

// async global -> LDS, 16 bytes per lane (lds dest: wave-uniform base + lane*16)
__device__ __forceinline__ void gld16(const void* g, void* l) {
    __builtin_amdgcn_global_load_lds(
        (const __attribute__((address_space(1))) void*)g,
        (__attribute__((address_space(3))) void*)l, 16, 0, 0);
}

// ---------------- K1: per-group normalize + banded fragment-major fp8 write + fp32 Gram ----
// (R17 512-thread version, unchanged.) xn8 layout (ulong units): idx = band64*8192 +
// kstep*256 + m*64 + slot; band64 = row>>6, m = (row>>4)&3, slot = oct*16 + (row&15).
__global__ __launch_bounds__(512) void k_normpos(const float* __restrict__ in,
                                                 unsigned long* __restrict__ xn8,
                                                 float* __restrict__ pos_sims,
                                                 float* __restrict__ min_pos,
                                                 unsigned* __restrict__ gmax,
                                                 float* __restrict__ accum,
                                                 unsigned* __restrict__ cnt) {
    __shared__ float4 srows4[8 * 257];
    __shared__ float spart[8][4];
    __shared__ float sinv[8];
    __shared__ float sg[8][8];

    int g = blockIdx.x;
    int t = threadIdx.x;
    int lane = t & 63;
    int w = t >> 6;
    int par = t >> 8;

    if (g == 0) {
        if (t == 0) { *gmax = 0u; *cnt = 0u; }
        if (t < 32) accum[t] = 0.f;
    }

    const float4* in4 = (const float4*)in;
    #pragma unroll
    for (int k = 0; k < 4; ++k) {
        float4 v = in4[(size_t)g * 2048 + k * 512 + t];
        int row = 2 * k + par;
        srows4[row * 257 + (t & 255)] = v;
        float ss = v.x * v.x + v.y * v.y + v.z * v.z + v.w * v.w;
        #pragma unroll
        for (int off = 1; off < 64; off <<= 1) ss += __shfl_xor(ss, off);
        if (lane == 0) spart[row][w & 3] = ss;
    }
    __syncthreads();
    if (t < 8) sinv[t] = rsqrtf(spart[t][0] + spart[t][1] + spart[t][2] + spart[t][3]);
    __syncthreads();

    {
        int i_row = t & 7;
        int oct  = (t >> 3) & 3;
        int k0b  = (t >> 5) & 7;
        int hi   = t >> 8;
        size_t base = (size_t)(g >> 3) * 8192 + (size_t)((g >> 1) & 3) * 64
                    + (size_t)(oct * 16 + (g & 1) * 8 + i_row);
        float inv = sinv[i_row];
        #pragma unroll
        for (int jj = 0; jj < 2; ++jj) {
            int k0 = k0b + (hi * 2 + jj) * 8;
            float4 v0 = srows4[i_row * 257 + k0 * 8 + oct * 2];
            float4 v1 = srows4[i_row * 257 + k0 * 8 + oct * 2 + 1];
            union { unsigned char c[8]; unsigned long u64; } o;
            o.c[0] = __hip_fp8_e4m3(v0.x * inv).__x;
            o.c[1] = __hip_fp8_e4m3(v0.y * inv).__x;
            o.c[2] = __hip_fp8_e4m3(v0.z * inv).__x;
            o.c[3] = __hip_fp8_e4m3(v0.w * inv).__x;
            o.c[4] = __hip_fp8_e4m3(v1.x * inv).__x;
            o.c[5] = __hip_fp8_e4m3(v1.y * inv).__x;
            o.c[6] = __hip_fp8_e4m3(v1.z * inv).__x;
            o.c[7] = __hip_fp8_e4m3(v1.w * inv).__x;
            xn8[base + (size_t)k0 * 256] = o.u64;
        }
    }

    int pair = t >> 3, a = pair >> 3, b = pair & 7, slice = t & 7;
    const float4* pa = srows4 + a * 257 + slice * 32;
    const float4* pb = srows4 + b * 257 + slice * 32;
    int j0 = ((pair << 1) + slice) & 31;
    float s = 0.f;
    #pragma unroll 8
    for (int i = 0; i < 32; ++i) {
        int j = (i + j0) & 31;
        float4 x = pa[j], y = pb[j];
        s += x.x * y.x + x.y * y.y + x.z * y.z + x.w * y.w;
    }
    s += __shfl_xor(s, 1);
    s += __shfl_xor(s, 2);
    s += __shfl_xor(s, 4);
    if (slice == 0) sg[a][b] = s * sinv[a] * sinv[b];
    __syncthreads();
    if (t < 8) {
        float mn = 1e30f;
        int idx = 0;
        #pragma unroll
        for (int b2 = 0; b2 < 8; ++b2) {
            if (b2 == t) continue;
            float v = sg[t][b2];
            mn = fminf(mn, v);
            pos_sims[(size_t)(g * 8 + t) * 8 + idx] = v;
            ++idx;
        }
        min_pos[g * 8 + t] = mn;
    }
}

// ---------------- K2: fp8 MFMA sim tiles; BK=128, 4 independent tile-waves ----------
// grid 520 x 256 threads = 2080 tile-waves; NO barriers. Per wave: depth-2 ring of
// 16KB stages (A 8KB | B 8KB = 16 contiguous 1KB gld16). 8 iterations of
// {vmcnt(16) -> 4 sub-k x (8 ds_read_b64 + 16 MFMA) -> lgkm(0) -> restage}.
// Same staged bytes as R12 (266MB) but 4x fewer DMA round-trips: discriminates
// latency-bound vs DMA-rate-bound.
__global__ __launch_bounds__(256) void k_neg(const unsigned long* __restrict__ xn8,
                                             const float* __restrict__ min_pos,
                                             float* __restrict__ sum_part,
                                             int* __restrict__ cnt_part,
                                             float* __restrict__ max_part,
                                             unsigned* __restrict__ gmax) {
    __shared__ char sbuf[4][2][16384];   // [wave][stage][A 8KB | B 8KB] = 128 KB

    int t = threadIdx.x;
    int w = t >> 6;          // wave id 0..3
    int l = t & 63;
    int u = blockIdx.x * 4 + w;   // tile unit 0..2079

    // decode triangular tile index (rt, ct), ct >= rt, over 64 bands
    int rt = 0, rem = u;
    while (rem >= NB - rt) { rem -= NB - rt; ++rt; }
    int ct = rt + rem;
    bool diag = (rt == ct);

    int R0 = rt * 64, C0 = ct * 64;
    int lrow = l & 15;
    int kgrp = l >> 4;

    float mA = min_pos[R0 + l];
    float mB = min_pos[C0 + l];
    asm volatile("s_waitcnt vmcnt(0)" ::: "memory");   // exact vmcnt bookkeeping below

    const char* xb = (const char*)xn8;
    const char* gA = xb + (size_t)rt * 65536 + (size_t)l * 16;
    const char* gB = xb + (size_t)ct * 65536 + (size_t)l * 16;
    char* ring = &sbuf[w][0][0];

    // stage s covers k-steps [4s,4s+4): A bytes [s*8192,(s+1)*8192), B likewise.
    #define STAGE(s_)                                                       \
        do {                                                                \
            char* d_ = ring + ((s_) & 1) * 16384;                           \
            _Pragma("unroll")                                               \
            for (int j = 0; j < 8; ++j) {                                   \
                gld16(gA + (size_t)(s_) * 8192 + j * 1024, d_ + j * 1024);  \
                gld16(gB + (size_t)(s_) * 8192 + j * 1024, d_ + 8192 + j * 1024); \
            }                                                               \
        } while (0)

    STAGE(0); STAGE(1);   // 32 loads in flight

    f32x4 zero = {0.f, 0.f, 0.f, 0.f};
    f32x4 acc[4][4];
    #pragma unroll
    for (int m = 0; m < 4; ++m)
        #pragma unroll
        for (int n = 0; n < 4; ++n) acc[m][n] = zero;

    for (int it = 0; it < 8; ++it) {
        // retire stage `it` (16 loads); keep stage it+1 (16) in flight
        if (it <= 6) asm volatile("s_waitcnt vmcnt(16)" ::: "memory");
        else         asm volatile("s_waitcnt vmcnt(0)"  ::: "memory");

        const char* buf = ring + (it & 1) * 16384;
        #pragma unroll
        for (int ks = 0; ks < 4; ++ks) {
            long a[4], b[4];
            #pragma unroll
            for (int m = 0; m < 4; ++m) {
                a[m] = *(const long*)(buf + ks * 2048 + m * 512 + l * 8);
                b[m] = *(const long*)(buf + 8192 + ks * 2048 + m * 512 + l * 8);
            }
            #pragma unroll
            for (int m = 0; m < 4; ++m)
                #pragma unroll
                for (int n = 0; n < 4; ++n)
                    acc[m][n] = __builtin_amdgcn_mfma_f32_16x16x32_fp8_fp8(
                        a[m], b[n], acc[m][n], 0, 0, 0);
        }

        // all 32 ds_reads of buf consumed -> safe to overwrite its ring slot
        asm volatile("s_waitcnt lgkmcnt(0)" ::: "memory");
        if (it <= 5) STAGE(it + 2);
    }
    #undef STAGE

    // ---- epilogue: row-band stats; col-band (transpose) stats for off-diag ----
    float allmax = -1e30f;

    float thB[4];
    #pragma unroll
    for (int n = 0; n < 4; ++n) thB[n] = __shfl(mB, n * 16 + lrow) - 0.05f;

    float colS[4] = {0.f, 0.f, 0.f, 0.f};
    float colM[4] = {-1e30f, -1e30f, -1e30f, -1e30f};
    int   colC[4] = {0, 0, 0, 0};

    #pragma unroll
    for (int m = 0; m < 4; ++m) {
        #pragma unroll
        for (int reg = 0; reg < 4; ++reg) {
            int lr = m * 16 + kgrp * 4 + reg;   // local row in [0,64)
            int grow = R0 + lr;
            float th = __shfl(mA, lr) - 0.05f;
            int gi = grow >> 3;
            float rs = 0.f, rm = -1e30f;
            int rc = 0;
            #pragma unroll
            for (int n = 0; n < 4; ++n) {
                int gcol = C0 + n * 16 + lrow;
                float s = acc[m][n][reg];
                allmax = fmaxf(allmax, s);
                if ((gcol >> 3) != gi) {
                    float e = softplus(ALPHA * (s - MARGIN));
                    rm = fmaxf(rm, s);
                    if (s > th) { rs += e; rc += 1; }
                    if (!diag) {
                        colM[n] = fmaxf(colM[n], s);
                        if (s > thB[n]) { colS[n] += e; colC[n] += 1; }
                    }
                }
            }
            #pragma unroll
            for (int off = 1; off < 16; off <<= 1) {
                rs += __shfl_xor(rs, off);
                rc += __shfl_xor(rc, off);
                rm = fmaxf(rm, __shfl_xor(rm, off));
            }
            if (lrow == 0) {
                sum_part[(size_t)grow * 64 + ct] = rs;
                cnt_part[(size_t)grow * 64 + ct] = rc;
                max_part[(size_t)grow * 64 + ct] = rm;
            }
        }
    }

    if (!diag) {
        #pragma unroll
        for (int n = 0; n < 4; ++n) {
            float cs = colS[n], cm = colM[n];
            int cc = colC[n];
            cs += __shfl_xor(cs, 16); cs += __shfl_xor(cs, 32);
            cc += __shfl_xor(cc, 16); cc += __shfl_xor(cc, 32);
            cm = fmaxf(cm, __shfl_xor(cm, 16));
            cm = fmaxf(cm, __shfl_xor(cm, 32));
            if (kgrp == 0) {
                int gcol = C0 + n * 16 + lrow;
                sum_part[(size_t)gcol * 64 + rt] = cs;
                cnt_part[(size_t)gcol * 64 + rt] = cc;
                max_part[(size_t)gcol * 64 + rt] = cm;
            }
        }
    }

    #pragma unroll
    for (int off = 1; off < 64; off <<= 1) allmax = fmaxf(allmax, __shfl_xor(allmax, off));
    if (l == 0) atomicMax(gmax, fkey(allmax));
}

// ---------------- K3: per-row combine (64 slots/row) + spread-atomic final mean ----------------
__global__ __launch_bounds__(256) void k_rowfinal(const float* __restrict__ sum_part,
                                                  const int* __restrict__ cnt_part,
                                                  const float* __restrict__ max_part,
                                                  const float* __restrict__ pos_sims,
                                                  const float* __restrict__ min_pos,
                                                  const unsigned* __restrict__ gmax,
                                                  float* __restrict__ accum,
                                                  unsigned* __restrict__ cnt,
                                                  float* __restrict__ out) {
    __shared__ float sloss[4];
    int row = blockIdx.x * 4 + (threadIdx.x >> 6);
    int lane = threadIdx.x & 63;
    float ns = sum_part[(size_t)row * 64 + lane];
    int nc = cnt_part[(size_t)row * 64 + lane];
    float nm = max_part[(size_t)row * 64 + lane];
    #pragma unroll
    for (int off = 1; off < 64; off <<= 1) {
        ns += __shfl_xor(ns, off);
        nc += __shfl_xor(nc, off);
        nm = fmaxf(nm, __shfl_xor(nm, off));
    }
    if (lane == 0) {
        float base = fmaxf(fdec(*gmax) - 0.1f, MARGIN + 0.2f);
        float neg_loss = (nc > 0) ? ns / (float)nc : softplus(ALPHA * (nm - MARGIN));
        float ps = 0.f;
        int pcnt = 0;
        float mn = min_pos[row];
        #pragma unroll
        for (int i = 0; i < NINST - 1; ++i) {
            float s = pos_sims[(size_t)row * 8 + i];
            if (s < base) { ps += softplus(-2.0f * (s - MARGIN)); pcnt++; }
        }
        float pos_loss = (pcnt > 0) ? ps / (float)pcnt : softplus(-2.0f * (mn - MARGIN));
        sloss[threadIdx.x >> 6] = pos_loss + neg_loss;
    }
    __syncthreads();
    if (threadIdx.x == 0) {
        float bs = sloss[0] + sloss[1] + sloss[2] + sloss[3];
        atomicAdd(&accum[blockIdx.x & 31], bs);
        __threadfence();
        unsigned old = atomicAdd(cnt, 1u);
        if (old == gridDim.x - 1) {
            __threadfence();
            float tot = 0.f;
            for (int j = 0; j < 32; ++j) tot += atomicAdd(&accum[j], 0.0f);
            out[0] = tot / (float)N;
        }
    }
}

extern "C" void kernel_launch(void* const* d_in, const int* in_sizes, int n_in,
                              void* d_out, int out_size, void* d_ws, size_t ws_size,
                              hipStream_t stream) {
    const float* in = (const float*)d_in[0];
    float* out = (float*)d_out;

    char* ws = (char*)d_ws;
    unsigned long* xn8 = (unsigned long*)(ws);                  // 4 MB (banded fragment-major)
    float*   min_pos  = (float*)(ws + 8388608 + 16384);         // 16 KB
    float*   pos_sims = (float*)(ws + 8388608 + 32768);         // 128 KB
    float*   sum_part = (float*)(ws + 8388608 + 32768 + 131072);            // 1 MB
    float*   max_part = (float*)(ws + 8388608 + 32768 + 131072 + 1048576);  // 1 MB
    int*     cnt_part = (int*)  (ws + 8388608 + 32768 + 131072 + 2097152);  // 1 MB
    unsigned* gmax    = (unsigned*)(ws + 8388608 + 32768 + 131072 + 3145728);
    float*   accum    = (float*)(ws + 8388608 + 32768 + 131072 + 3145728 + 128);  // 32 floats
    unsigned* cnt     = (unsigned*)(ws + 8388608 + 32768 + 131072 + 3145728 + 256);

    k_normpos<<<NGROUP, 512, 0, stream>>>(in, xn8, pos_sims, min_pos, gmax, accum, cnt);
    k_neg<<<NTILE / 4, 256, 0, stream>>>(xn8, min_pos, sum_part, cnt_part, max_part, gmax);
    k_rowfinal<<<N / 4, 256, 0, stream>>>(sum_part, cnt_part, max_part, pos_sims, min_pos,
                                          gmax, accum, cnt, out);
}

// Round 22
// 99.273 us; speedup vs baseline: 1.6977x; 1.2022x over previous
//
#include <hip/hip_runtime.h>
#include <hip/hip_bf16.h>
#include <hip/hip_fp8.h>
#include <math.h>

#define N 4096
#define D 1024
#define NINST 8
#define NGROUP (N / NINST)
#define ALPHA 20.0f
#define MARGIN 0.5f
#define NB 64            // 64-row bands
#define NTILE (NB * (NB + 1) / 2)   // 2080 triangular tiles

typedef __attribute__((ext_vector_type(4))) float f32x4;

__device__ __forceinline__ unsigned fkey(float f) {
    int b = __float_as_int(f);
    return (b >= 0) ? ((unsigned)b | 0x80000000u) : ~(unsigned)b;
}
__device__ __forceinline__ float fdec(unsigned u) {
    int b = (u & 0x80000000u) ? (int)(u ^ 0x80000000u) : ~(int)u;
    return __int_as_float(b);
}

// stable fast softplus: log1p(exp(x)) = max(x,0) + log(1 + exp(-|x|))
__device__ __forceinline__ float softplus(float x) {
    float z = __expf(-fabsf(x));
    return fmaxf(x, 0.0f) + __logf(1.0f + z);
}

// async global -> LDS, 16 bytes per lane (lds dest: wave-uniform base + lane*16)
__device__ __forceinline__ void gld16(const void* g, void* l) {
    __builtin_amdgcn_global_load_lds(
        (const __attribute__((address_space(1))) void*)g,
        (__attribute__((address_space(3))) void*)l, 16, 0, 0);
}

// ---------------- K1: per-group normalize + K-MAJOR fragment-major fp8 write + fp32 Gram ----
// xn8 layout (ulong units): idx = kstep*16384 + band64*256 + m*64 + slot, where
// band64 = row>>6, m = (row>>4)&3, slot = oct*16 + (row&15); the ulong holds row's
// fp8 bytes [kstep*32 + oct*8, +8). One (kstep,band) panel = 2KB contiguous, but
// consecutive k-steps are 128KB apart and different bands 2KB apart -> a k_neg
// stage's 4 bursts are widely separated (channel-spread probe).
__global__ __launch_bounds__(512) void k_normpos(const float* __restrict__ in,
                                                 unsigned long* __restrict__ xn8,
                                                 float* __restrict__ pos_sims,
                                                 float* __restrict__ min_pos,
                                                 unsigned* __restrict__ gmax,
                                                 float* __restrict__ accum,
                                                 unsigned* __restrict__ cnt) {
    __shared__ float4 srows4[8 * 257];
    __shared__ float spart[8][4];
    __shared__ float sinv[8];
    __shared__ float sg[8][8];

    int g = blockIdx.x;
    int t = threadIdx.x;
    int lane = t & 63;
    int w = t >> 6;
    int par = t >> 8;

    if (g == 0) {
        if (t == 0) { *gmax = 0u; *cnt = 0u; }
        if (t < 32) accum[t] = 0.f;
    }

    const float4* in4 = (const float4*)in;
    #pragma unroll
    for (int k = 0; k < 4; ++k) {
        float4 v = in4[(size_t)g * 2048 + k * 512 + t];
        int row = 2 * k + par;
        srows4[row * 257 + (t & 255)] = v;
        float ss = v.x * v.x + v.y * v.y + v.z * v.z + v.w * v.w;
        #pragma unroll
        for (int off = 1; off < 64; off <<= 1) ss += __shfl_xor(ss, off);
        if (lane == 0) spart[row][w & 3] = ss;
    }
    __syncthreads();
    if (t < 8) sinv[t] = rsqrtf(spart[t][0] + spart[t][1] + spart[t][2] + spart[t][3]);
    __syncthreads();

    {
        int i_row = t & 7;
        int oct  = (t >> 3) & 3;
        int k0b  = (t >> 5) & 7;
        int hi   = t >> 8;
        size_t base = (size_t)(g >> 3) * 256 + (size_t)((g >> 1) & 3) * 64
                    + (size_t)(oct * 16 + (g & 1) * 8 + i_row);
        float inv = sinv[i_row];
        #pragma unroll
        for (int jj = 0; jj < 2; ++jj) {
            int k0 = k0b + (hi * 2 + jj) * 8;
            float4 v0 = srows4[i_row * 257 + k0 * 8 + oct * 2];
            float4 v1 = srows4[i_row * 257 + k0 * 8 + oct * 2 + 1];
            union { unsigned char c[8]; unsigned long u64; } o;
            o.c[0] = __hip_fp8_e4m3(v0.x * inv).__x;
            o.c[1] = __hip_fp8_e4m3(v0.y * inv).__x;
            o.c[2] = __hip_fp8_e4m3(v0.z * inv).__x;
            o.c[3] = __hip_fp8_e4m3(v0.w * inv).__x;
            o.c[4] = __hip_fp8_e4m3(v1.x * inv).__x;
            o.c[5] = __hip_fp8_e4m3(v1.y * inv).__x;
            o.c[6] = __hip_fp8_e4m3(v1.z * inv).__x;
            o.c[7] = __hip_fp8_e4m3(v1.w * inv).__x;
            xn8[(size_t)k0 * 16384 + base] = o.u64;
        }
    }

    int pair = t >> 3, a = pair >> 3, b = pair & 7, slice = t & 7;
    const float4* pa = srows4 + a * 257 + slice * 32;
    const float4* pb = srows4 + b * 257 + slice * 32;
    int j0 = ((pair << 1) + slice) & 31;
    float s = 0.f;
    #pragma unroll 8
    for (int i = 0; i < 32; ++i) {
        int j = (i + j0) & 31;
        float4 x = pa[j], y = pb[j];
        s += x.x * y.x + x.y * y.y + x.z * y.z + x.w * y.w;
    }
    s += __shfl_xor(s, 1);
    s += __shfl_xor(s, 2);
    s += __shfl_xor(s, 4);
    if (slice == 0) sg[a][b] = s * sinv[a] * sinv[b];
    __syncthreads();
    if (t < 8) {
        float mn = 1e30f;
        int idx = 0;
        #pragma unroll
        for (int b2 = 0; b2 < 8; ++b2) {
            if (b2 == t) continue;
            float v = sg[t][b2];
            mn = fminf(mn, v);
            pos_sims[(size_t)(g * 8 + t) * 8 + idx] = v;
            ++idx;
        }
        min_pos[g * 8 + t] = mn;
    }
}

// ---------------- K2: fp8 MFMA sim tiles; 4 tile-waves, K-MAJOR xn8 ----------
// (R12 schedule, unchanged.) grid 520 x 256 = 2080 tile-waves; NO barriers; per
// wave depth-3 ring (12 KB); per k-step: vmcnt(8) -> 8 ds_read_b64 -> 16 MFMA ->
// lgkm(0) -> restage. Only the GLOBAL ADDRESSES changed: stage s loads 4 bursts at
// s*131072 + {rt,ct}*2048 (+1024) -- widely channel-spread vs the old contiguous band.
__global__ __launch_bounds__(256, 2) void k_neg(const unsigned long* __restrict__ xn8,
                                                const float* __restrict__ min_pos,
                                                float* __restrict__ sum_part,
                                                int* __restrict__ cnt_part,
                                                float* __restrict__ max_part,
                                                unsigned* __restrict__ gmax) {
    __shared__ char sbuf[4][3][4096];   // [wave][stage][A 2KB | B 2KB] = 48 KB

    int t = threadIdx.x;
    int w = t >> 6;          // wave id 0..3
    int l = t & 63;
    int u = blockIdx.x * 4 + w;   // tile unit 0..2079

    // decode triangular tile index (rt, ct), ct >= rt, over 64 bands
    int rt = 0, rem = u;
    while (rem >= NB - rt) { rem -= NB - rt; ++rt; }
    int ct = rt + rem;
    bool diag = (rt == ct);

    int R0 = rt * 64, C0 = ct * 64;
    int lrow = l & 15;
    int kgrp = l >> 4;

    float mA = min_pos[R0 + l];
    float mB = min_pos[C0 + l];
    asm volatile("s_waitcnt vmcnt(0)" ::: "memory");   // exact vmcnt bookkeeping below

    const char* xb = (const char*)xn8;
    const char* gA = xb + (size_t)rt * 2048 + (size_t)l * 16;
    const char* gB = xb + (size_t)ct * 2048 + (size_t)l * 16;
    char* ring = &sbuf[w][0][0];

    #define STAGE(s_)                                                   \
        do {                                                            \
            char* d_ = ring + ((s_) % 3) * 4096;                        \
            gld16(gA + (size_t)(s_) * 131072,        d_);               \
            gld16(gA + (size_t)(s_) * 131072 + 1024, d_ + 1024);        \
            gld16(gB + (size_t)(s_) * 131072,        d_ + 2048);        \
            gld16(gB + (size_t)(s_) * 131072 + 1024, d_ + 3072);        \
        } while (0)

    STAGE(0); STAGE(1); STAGE(2);

    f32x4 zero = {0.f, 0.f, 0.f, 0.f};
    f32x4 acc[4][4];
    #pragma unroll
    for (int m = 0; m < 4; ++m)
        #pragma unroll
        for (int n = 0; n < 4; ++n) acc[m][n] = zero;

    for (int it = 0; it < 32; ++it) {
        // retire stage `it` (4 loads); keep up to 2 stages in flight
        if (it <= 29)      asm volatile("s_waitcnt vmcnt(8)" ::: "memory");
        else if (it == 30) asm volatile("s_waitcnt vmcnt(4)" ::: "memory");
        else               asm volatile("s_waitcnt vmcnt(0)" ::: "memory");

        const char* buf = ring + (it % 3) * 4096;
        long a[4], b[4];
        #pragma unroll
        for (int m = 0; m < 4; ++m) {
            a[m] = *(const long*)(buf + m * 512 + l * 8);
            b[m] = *(const long*)(buf + 2048 + m * 512 + l * 8);
        }

        // MFMAs overlap ds_read returns (compiler inserts partial lgkm waits)
        #pragma unroll
        for (int m = 0; m < 4; ++m)
            #pragma unroll
            for (int n = 0; n < 4; ++n)
                acc[m][n] = __builtin_amdgcn_mfma_f32_16x16x32_fp8_fp8(
                    a[m], b[n], acc[m][n], 0, 0, 0);

        // all reads of buf consumed -> safe to overwrite its ring slot
        asm volatile("s_waitcnt lgkmcnt(0)" ::: "memory");
        if (it <= 28) STAGE(it + 3);
    }
    #undef STAGE

    // ---- epilogue: row-band stats; col-band (transpose) stats for off-diag ----
    float allmax = -1e30f;

    float thB[4];
    #pragma unroll
    for (int n = 0; n < 4; ++n) thB[n] = __shfl(mB, n * 16 + lrow) - 0.05f;

    float colS[4] = {0.f, 0.f, 0.f, 0.f};
    float colM[4] = {-1e30f, -1e30f, -1e30f, -1e30f};
    int   colC[4] = {0, 0, 0, 0};

    #pragma unroll
    for (int m = 0; m < 4; ++m) {
        #pragma unroll
        for (int reg = 0; reg < 4; ++reg) {
            int lr = m * 16 + kgrp * 4 + reg;   // local row in [0,64)
            int grow = R0 + lr;
            float th = __shfl(mA, lr) - 0.05f;
            int gi = grow >> 3;
            float rs = 0.f, rm = -1e30f;
            int rc = 0;
            #pragma unroll
            for (int n = 0; n < 4; ++n) {
                int gcol = C0 + n * 16 + lrow;
                float s = acc[m][n][reg];
                allmax = fmaxf(allmax, s);
                if ((gcol >> 3) != gi) {
                    float e = softplus(ALPHA * (s - MARGIN));
                    rm = fmaxf(rm, s);
                    if (s > th) { rs += e; rc += 1; }
                    if (!diag) {
                        colM[n] = fmaxf(colM[n], s);
                        if (s > thB[n]) { colS[n] += e; colC[n] += 1; }
                    }
                }
            }
            #pragma unroll
            for (int off = 1; off < 16; off <<= 1) {
                rs += __shfl_xor(rs, off);
                rc += __shfl_xor(rc, off);
                rm = fmaxf(rm, __shfl_xor(rm, off));
            }
            if (lrow == 0) {
                sum_part[(size_t)grow * 64 + ct] = rs;
                cnt_part[(size_t)grow * 64 + ct] = rc;
                max_part[(size_t)grow * 64 + ct] = rm;
            }
        }
    }

    if (!diag) {
        #pragma unroll
        for (int n = 0; n < 4; ++n) {
            float cs = colS[n], cm = colM[n];
            int cc = colC[n];
            cs += __shfl_xor(cs, 16); cs += __shfl_xor(cs, 32);
            cc += __shfl_xor(cc, 16); cc += __shfl_xor(cc, 32);
            cm = fmaxf(cm, __shfl_xor(cm, 16));
            cm = fmaxf(cm, __shfl_xor(cm, 32));
            if (kgrp == 0) {
                int gcol = C0 + n * 16 + lrow;
                sum_part[(size_t)gcol * 64 + rt] = cs;
                cnt_part[(size_t)gcol * 64 + rt] = cc;
                max_part[(size_t)gcol * 64 + rt] = cm;
            }
        }
    }

    #pragma unroll
    for (int off = 1; off < 64; off <<= 1) allmax = fmaxf(allmax, __shfl_xor(allmax, off));
    if (l == 0) atomicMax(gmax, fkey(allmax));
}

// ---------------- K3: per-row combine (64 slots/row) + spread-atomic final mean ----------------
__global__ __launch_bounds__(256) void k_rowfinal(const float* __restrict__ sum_part,
                                                  const int* __restrict__ cnt_part,
                                                  const float* __restrict__ max_part,
                                                  const float* __restrict__ pos_sims,
                                                  const float* __restrict__ min_pos,
                                                  const unsigned* __restrict__ gmax,
                                                  float* __restrict__ accum,
                                                  unsigned* __restrict__ cnt,
                                                  float* __restrict__ out) {
    __shared__ float sloss[4];
    int row = blockIdx.x * 4 + (threadIdx.x >> 6);
    int lane = threadIdx.x & 63;
    float ns = sum_part[(size_t)row * 64 + lane];
    int nc = cnt_part[(size_t)row * 64 + lane];
    float nm = max_part[(size_t)row * 64 + lane];
    #pragma unroll
    for (int off = 1; off < 64; off <<= 1) {
        ns += __shfl_xor(ns, off);
        nc += __shfl_xor(nc, off);
        nm = fmaxf(nm, __shfl_xor(nm, off));
    }
    if (lane == 0) {
        float base = fmaxf(fdec(*gmax) - 0.1f, MARGIN + 0.2f);
        float neg_loss = (nc > 0) ? ns / (float)nc : softplus(ALPHA * (nm - MARGIN));
        float ps = 0.f;
        int pcnt = 0;
        float mn = min_pos[row];
        #pragma unroll
        for (int i = 0; i < NINST - 1; ++i) {
            float s = pos_sims[(size_t)row * 8 + i];
            if (s < base) { ps += softplus(-2.0f * (s - MARGIN)); pcnt++; }
        }
        float pos_loss = (pcnt > 0) ? ps / (float)pcnt : softplus(-2.0f * (mn - MARGIN));
        sloss[threadIdx.x >> 6] = pos_loss + neg_loss;
    }
    __syncthreads();
    if (threadIdx.x == 0) {
        float bs = sloss[0] + sloss[1] + sloss[2] + sloss[3];
        atomicAdd(&accum[blockIdx.x & 31], bs);
        __threadfence();
        unsigned old = atomicAdd(cnt, 1u);
        if (old == gridDim.x - 1) {
            __threadfence();
            float tot = 0.f;
            for (int j = 0; j < 32; ++j) tot += atomicAdd(&accum[j], 0.0f);
            out[0] = tot / (float)N;
        }
    }
}

extern "C" void kernel_launch(void* const* d_in, const int* in_sizes, int n_in,
                              void* d_out, int out_size, void* d_ws, size_t ws_size,
                              hipStream_t stream) {
    const float* in = (const float*)d_in[0];
    float* out = (float*)d_out;

    char* ws = (char*)d_ws;
    unsigned long* xn8 = (unsigned long*)(ws);                  // 4 MB (k-major fragment-major)
    float*   min_pos  = (float*)(ws + 8388608 + 16384);         // 16 KB
    float*   pos_sims = (float*)(ws + 8388608 + 32768);         // 128 KB
    float*   sum_part = (float*)(ws + 8388608 + 32768 + 131072);            // 1 MB
    float*   max_part = (float*)(ws + 8388608 + 32768 + 131072 + 1048576);  // 1 MB
    int*     cnt_part = (int*)  (ws + 8388608 + 32768 + 131072 + 2097152);  // 1 MB
    unsigned* gmax    = (unsigned*)(ws + 8388608 + 32768 + 131072 + 3145728);
    float*   accum    = (float*)(ws + 8388608 + 32768 + 131072 + 3145728 + 128);  // 32 floats
    unsigned* cnt     = (unsigned*)(ws + 8388608 + 32768 + 131072 + 3145728 + 256);

    k_normpos<<<NGROUP, 512, 0, stream>>>(in, xn8, pos_sims, min_pos, gmax, accum, cnt);
    k_neg<<<NTILE / 4, 256, 0, stream>>>(xn8, min_pos, sum_part, cnt_part, max_part, gmax);
    k_rowfinal<<<N / 4, 256, 0, stream>>>(sum_part, cnt_part, max_part, pos_sims, min_pos,
                                          gmax, accum, cnt, out);
}